// Round 8
// baseline (193.033 us; speedup 1.0000x reference)
//
#include <hip/hip_runtime.h>
#include <math.h>

#define D       256
#define KCODES  1024
#define NROWS   65536
#define BETA    0.25f
#define MARGIN  1e-3f
#define MAXSURV 7

typedef __attribute__((ext_vector_type(8))) short bf16x8;
typedef __attribute__((ext_vector_type(4))) float f32x4;

__device__ __forceinline__ unsigned int bf16_rne(float f) {
    unsigned int u = __float_as_uint(f);
    return (u + 0x7FFFu + ((u >> 16) & 1u)) >> 16;   // RNE bf16 (inputs are finite/normal)
}
__device__ __forceinline__ f32x4 mfma16(bf16x8 a, bf16x8 b, f32x4 c) {
    return __builtin_amdgcn_mfma_f32_16x16x32_bf16(a, b, c, 0, 0, 0);
}

// ---------- codebook -> bf16 (hi only, RNE): cs[k][0:256]; e2f exact ----------
__global__ __launch_bounds__(256) void split_cb_kernel(const float* __restrict__ cb,
                                                       ushort* __restrict__ cs,
                                                       float* __restrict__ e2f) {
    int code = blockIdx.x * 4 + (threadIdx.x >> 6);
    int lane = threadIdx.x & 63;
    float4 v = ((const float4*)(cb + (size_t)code * D))[lane];
    double s = (double)v.x * v.x + (double)v.y * v.y +
               (double)v.z * v.z + (double)v.w * v.w;
    ushort* ph = cs + (size_t)code * 256 + lane * 4;
    ph[0] = (ushort)bf16_rne(v.x); ph[1] = (ushort)bf16_rne(v.y);
    ph[2] = (ushort)bf16_rne(v.z); ph[3] = (ushort)bf16_rne(v.w);
    #pragma unroll
    for (int off = 32; off > 0; off >>= 1) s += __shfl_down(s, off, 64);
    if (lane == 0) e2f[code] = (float)s;
}

// ---------- v9: v8 + XOR-swizzled B tile (T2). Unpadded 512-B rows; granule index
// (byte/16) XOR'd with (row&7) on BOTH write and read -> each row's 16-B granules
// spread across all 8 span-slots, killing the ~8-way b128 conflict the 264-pitch
// layout had (8.4M conflict cycles ~ 13 us/CU). Top-2 update via min/max network
// (3 ops vs 5, identical result for distinct keys). Outputs bit-identical to v8. ----------
__global__ __launch_bounds__(512, 4) void screen_kernel(
    const float* __restrict__ x, const ushort* __restrict__ cs,
    const float* __restrict__ e2f, const float* __restrict__ cb,
    float* __restrict__ out_idxf, unsigned int* __restrict__ counts,
    float* __restrict__ y, float* __restrict__ msepart)
{
    __shared__ __attribute__((aligned(16))) ushort Bt[2][32 * 256];  // 2 x 16 KB, swizzled
    __shared__ unsigned mrg[128 * 33];         // merge scratch (pitch 33 dwords)
    __shared__ float x2s[128];                 // per-local-row exact |x|^2
    #define MRG(r, j) mrg[(r) * 33 + (j)]

    const int tid  = threadIdx.x;
    const int wave = tid >> 6, lane = tid & 63;
    const int quad = lane >> 4, m = lane & 15;
    const int rowBase = blockIdx.x * 128;
    const int wrb = rowBase + wave * 16;       // this wave's 16 rows (1 M-tile)

    // ---- issue tile-0 staging loads first: latency hides under the A-fragment build ----
    const int sc = tid & 31, sp = tid >> 5;    // staging: code 0..31, part 0..15 (16 ushorts)
    const int swW = (sc & 7) << 4;             // write-side XOR (row = sc)
    const int wb0 = (sc * 512 + sp * 32) ^ swW;
    const int wb1 = (sc * 512 + sp * 32 + 16) ^ swW;
    bf16x8 stg[2];
    {
        const ushort* src = cs + (size_t)sc * 256 + sp * 16;
        stg[0] = *(const bf16x8*)&src[0];
        stg[1] = *(const bf16x8*)&src[8];
    }

    // ---- build A fragment (bf16 hi) in registers from fp32 x; accumulate exact x2 ----
    bf16x8 af[8];                              // 32 VGPRs
    {
        const float* xr = x + (size_t)(wrb + m) * D;
        double s = 0.0;
        #pragma unroll
        for (int c = 0; c < 8; ++c) {
            float4 f0 = *(const float4*)&xr[c * 32 + quad * 8];
            float4 f1 = *(const float4*)&xr[c * 32 + quad * 8 + 4];
            s += (double)f0.x * f0.x + (double)f0.y * f0.y +
                 (double)f0.z * f0.z + (double)f0.w * f0.w;
            s += (double)f1.x * f1.x + (double)f1.y * f1.y +
                 (double)f1.z * f1.z + (double)f1.w * f1.w;
            float ff[8] = {f0.x, f0.y, f0.z, f0.w, f1.x, f1.y, f1.z, f1.w};
            #pragma unroll
            for (int j = 0; j < 8; ++j) af[c][j] = (short)bf16_rne(ff[j]);
        }
        s += __shfl_xor(s, 16, 64);
        s += __shfl_xor(s, 32, 64);
        if (quad == 0) x2s[wave * 16 + m] = (float)s;
    }

    // ---- packed top-2 per row-reg over this lane's code class ----
    unsigned u1[4], u2[4];
    #pragma unroll
    for (int r = 0; r < 4; ++r) { u1[r] = 0xFFFFFFFFu; u2[r] = 0xFFFFFFFFu; }

    const int swR = (m & 7) << 4;              // read-side XOR ((nt*16+m)&7 == m&7)

    // Pipeline per kt:  [ds_write stg(kt) -> buf[kt&1]]  barrier
    //                   [issue global loads stg := tile kt+1]  [compute(kt) from buf[kt&1]]
    for (int kt = 0; kt < KCODES / 32; ++kt) {
        {
            char* dstb = (char*)&Bt[kt & 1][0];
            *(bf16x8*)(dstb + wb0) = stg[0];
            *(bf16x8*)(dstb + wb1) = stg[1];
        }
        __syncthreads();                        // buf[kt&1] visible to all waves
        if (kt < KCODES / 32 - 1) {
            const ushort* src = cs + (size_t)((kt + 1) * 32 + sc) * 256 + sp * 16;
            stg[0] = *(const bf16x8*)&src[0];
            stg[1] = *(const bf16x8*)&src[8];
        }

        // e2 prefetch (+0.5 pack bias folded in) before the MFMA clusters
        float e2pa = e2f[kt * 32 + m] + 0.5f;
        float e2pb = e2f[kt * 32 + 16 + m] + 0.5f;

        const char* Bcur = (const char*)&Bt[kt & 1][0];
        #pragma unroll
        for (int nt = 0; nt < 2; ++nt) {
            f32x4 acc = {0.f, 0.f, 0.f, 0.f};
            const int base = (nt * 16 + m) * 512 + quad * 16;
            __builtin_amdgcn_s_setprio(1);
            #pragma unroll
            for (int c = 0; c < 8; ++c) {
                bf16x8 bh = *(const bf16x8*)(Bcur + ((base + c * 64) ^ swR));
                acc = mfma16(af[c], bh, acc);
            }
            __builtin_amdgcn_s_setprio(0);
            unsigned kcode = kt * 32 + nt * 16 + m;
            float e2p = nt ? e2pb : e2pa;
            #pragma unroll
            for (int r = 0; r < 4; ++r) {
                float d = fmaf(-2.f, acc[r], e2p);              // dist + 0.5 (> 0)
                unsigned u = (__float_as_uint(d) & 0xFFFFFC00u) | kcode;
                u2[r] = min(max(u, u1[r]), u2[r]);              // sorting network:
                u1[r] = min(u, u1[r]);                          // 3 ops, exact (keys distinct)
            }
        }
    }

    // ---- per-row merge: 8 waves x 16 rows = 128 rows, single phase ----
    #pragma unroll
    for (int r = 0; r < 4; ++r) {
        int rowloc = wave * 16 + quad * 4 + r;
        MRG(rowloc, m * 2 + 0) = u1[r];
        MRG(rowloc, m * 2 + 1) = u2[r];
    }
    __syncthreads();
    if (tid < 128) {
        unsigned umin = 0xFFFFFFFFu;
        #pragma unroll
        for (int j = 0; j < 32; ++j) umin = min(umin, MRG(tid, j));
        float dfloor = __uint_as_float(umin & 0xFFFFFC00u);
        unsigned limu = (__float_as_uint(dfloor + MARGIN) & 0xFFFFFC00u) | 1023u;
        ushort out[8] = {0, 0, 0, 0, 0, 0, 0, 0};
        int cnt = 0;
        for (int j = 0; j < 32; ++j) {
            unsigned u = MRG(tid, j);
            if (u <= limu && cnt < MAXSURV) { out[1 + cnt] = (ushort)(u & 1023u); ++cnt; }
        }
        out[0] = (ushort)cnt;
        // park survivors in the first 16 B of this thread's own merge row (reads done)
        *(bf16x8*)&mrg[tid * 33] = *(bf16x8*)out;
    }
    __syncthreads();                            // survivor lists visible to all waves

    // ---- fused rescore/gather tail: each wave finishes its own 16 rows ----
    #pragma unroll 2
    for (int i = 0; i < 16; ++i) {
        int rl  = wave * 16 + i;
        int row = rowBase + rl;
        const ushort* lst = (const ushort*)&mrg[rl * 33];
        int cnt = lst[0];
        float4 xv = ((const float4*)(x + (size_t)row * D))[lane];

        int bk;
        if (cnt == 1) {
            bk = lst[1];                        // fast path: single survivor
        } else {
            float x2 = x2s[rl];
            float bestd = 1e30f;
            int   bestk = 0;
            for (int s = 0; s < cnt; ++s) {
                int k = lst[1 + s];
                float4 cv = ((const float4*)(cb + (size_t)k * D))[lane];
                double p = (double)xv.x * cv.x + (double)xv.y * cv.y +
                           (double)xv.z * cv.z + (double)xv.w * cv.w;
                #pragma unroll
                for (int off = 32; off > 0; off >>= 1) p += __shfl_down(p, off, 64);
                float simf = (float)p;          // correctly-rounded f32 sim (lane 0 exact)
                float tt   = x2 + e2f[k];       // fl32(x2+e2)
                float dq   = tt - 2.0f * simf;  // reference comparator
                if (dq < bestd || (dq == bestd && k < bestk)) { bestd = dq; bestk = k; }
            }
            bk = __shfl(bestk, 0, 64);          // lane 0 had the exact sums
        }
        if (lane == 0) {
            out_idxf[row] = (float)bk;
            atomicAdd(&counts[bk], 1u);         // 1024 distinct addresses -> low contention
        }
        // gather + y + mse partial (identical op order to old rescore_kernel)
        float4 q = ((const float4*)(cb + (size_t)bk * D))[lane];
        float4 dv;
        dv.x = q.x - xv.x; dv.y = q.y - xv.y; dv.z = q.z - xv.z; dv.w = q.w - xv.w;
        float4 yv;
        yv.x = xv.x + dv.x; yv.y = xv.y + dv.y; yv.z = xv.z + dv.z; yv.w = xv.w + dv.w;
        ((float4*)(y + (size_t)row * D))[lane] = yv;
        float s = dv.x * dv.x + dv.y * dv.y + dv.z * dv.z + dv.w * dv.w;
        #pragma unroll
        for (int off = 32; off > 0; off >>= 1) s += __shfl_down(s, off, 64);
        if (lane == 0) msepart[row] = s;        // plain store, no atomic
    }
    #undef MRG
}

// ---------- final scalars: reduce msepart + counts -> loss, perplexity, usage, H ----------
__global__ __launch_bounds__(1024) void stats_kernel(
    const unsigned int* __restrict__ counts, const float* __restrict__ msepart,
    float* __restrict__ outs)
{
    int t = threadIdx.x;
    // mse partial reduction: 64 coalesced strided reads per thread
    float ms = 0.f;
    #pragma unroll
    for (int j = 0; j < 64; ++j) ms += msepart[t + 1024 * j];

    float p = (float)counts[t] * (1.0f / 65536.0f);
    float h = -p * log2f(p + 1e-10f);
    float u = (p > 0.f) ? 1.f : 0.f;
    #pragma unroll
    for (int off = 32; off > 0; off >>= 1) {
        h  += __shfl_down(h,  off, 64);
        u  += __shfl_down(u,  off, 64);
        ms += __shfl_down(ms, off, 64);
    }
    __shared__ float hs[16], us[16], mss[16];
    int lane = t & 63, w = t >> 6;
    if (lane == 0) { hs[w] = h; us[w] = u; mss[w] = ms; }
    __syncthreads();
    if (t == 0) {
        float H = 0.f, U = 0.f, M = 0.f;
        #pragma unroll
        for (int i = 0; i < 16; ++i) { H += hs[i]; U += us[i]; M += mss[i]; }
        float m = M * (1.0f / 16777216.0f);
        float loss = BETA * m + m;
        float perp = expf(H * 0.69314718055994530942f);
        outs[0] = loss;
        outs[1] = perp;
        outs[2] = U * (1.0f / 1024.0f);
        outs[3] = H;
    }
}

extern "C" void kernel_launch(void* const* d_in, const int* in_sizes, int n_in,
                              void* d_out, int out_size, void* d_ws, size_t ws_size,
                              hipStream_t stream) {
    const float* x  = (const float*)d_in[0];   // [65536, 256]
    const float* cb = (const float*)d_in[1];   // [1024, 256]
    float* out      = (float*)d_out;

    float* y        = out;                      // 16,777,216
    float* out_idxf = out + 16777216;           // 65,536
    float* outs     = out + 16777216 + 65536;   // loss, perp, usage, H

    // ws layout (bytes):
    // [262144  .. 266239]  e2f (1024 f32)
    // [266240  .. 270335]  counts (1024 u32)
    // [1318976 .. 1843263] cs (1024 x 256 ushort, bf16 hi)
    // [1843264 .. 2105407] msepart (65536 f32)
    float*        e2f     = (float*)((char*)d_ws + 262144);
    unsigned int* counts  = (unsigned int*)((char*)d_ws + 266240);
    ushort*       cs      = (ushort*)((char*)d_ws + 1318976);
    float*        msepart = (float*)((char*)d_ws + 1843264);

    hipMemsetAsync((char*)d_ws + 266240, 0, 4096, stream);  // counts
    split_cb_kernel<<<KCODES / 4, 256, 0, stream>>>(cb, cs, e2f);
    screen_kernel<<<NROWS / 128, 512, 0, stream>>>(x, cs, e2f, cb,
                                                   out_idxf, counts, y, msepart);
    stats_kernel<<<1, 1024, 0, stream>>>(counts, msepart, outs);
}